// Round 6
// baseline (701.804 us; speedup 1.0000x reference)
//
#include <hip/hip_runtime.h>

#define BB 256
#define SS 1024
#define TT 128
#define ST 126          // START state (column ST of trans = -1e4)
#define EN 127          // END state   (row EN of trans = -1e4)
#define IMIN -10000.0f
#define L2E 1.4426950408889634f
#define LN2f 0.6931471805599453f

// One block per batch, 128 threads (2 waves). Thread i owns state row i.
// P[i][j] = 2^(trans[i][j]*log2e - rm_i) held in 128 VGPRs (full row).
// v[j] = 2^(A[j] - sh) in LDS (128 floats), sh block-uniform (anchor = state 0).
// Per step:  tot_i = sum_j P[i][j] * v[j]        (128 in-lane FMAs)
//            dsh   = log2(v[0])                  (uniform, no reduce)
//            v'_i  = tot_i * 2^(feat_i*L2E + rm_i - dsh);   sh += dsh
__global__ __launch_bounds__(128) void crf_fwd(const float* __restrict__ feats,
                                               const int* __restrict__ blen,
                                               const float* __restrict__ trans,
                                               float* __restrict__ out)
{
    const int i = threadIdx.x;   // state row 0..127
    const int b = blockIdx.x;

    __shared__ __align__(16) float vbuf[2][TT];
    __shared__ __align__(16) float featbuf[2][8 * TT];
    __shared__ __align__(16) float red[8];

    const float* fb = feats + (size_t)b * (SS * TT);
    const int L = blen[b];

    // stage feature chunk 0 (steps 0..7): 1024 floats = 2 float4 per thread
    {
        float4 c0 = *(const float4*)(fb + i * 4);
        float4 c1 = *(const float4*)(fb + 512 + i * 4);
        *(float4*)(&featbuf[0][i * 4]) = c0;
        *(float4*)(&featbuf[0][512 + i * 4]) = c1;
    }
    float f0 = fb[i];   // step-0 feature, direct (coalesced dword)

    // full transition row -> registers, base-2 units
    float4 P[32];
    {
        const float* trow = trans + i * TT;
        #pragma unroll
        for (int k = 0; k < 32; ++k) {
            float4 tv = *(const float4*)(trow + 4 * k);
            P[k].x = tv.x * L2E; P[k].y = tv.y * L2E;
            P[k].z = tv.z * L2E; P[k].w = tv.w * L2E;
        }
    }
    float rm = -3.4e38f;
    #pragma unroll
    for (int k = 0; k < 32; ++k)
        rm = fmaxf(rm, fmaxf(fmaxf(P[k].x, P[k].y), fmaxf(P[k].z, P[k].w)));

    // normalize P and row-sum S
    float S = 0.f;
    #pragma unroll
    for (int k = 0; k < 32; ++k) {
        P[k].x = exp2f(P[k].x - rm); P[k].y = exp2f(P[k].y - rm);
        P[k].z = exp2f(P[k].z - rm); P[k].w = exp2f(P[k].w - rm);
        S += (P[k].x + P[k].y) + (P[k].z + P[k].w);
    }

    // exact step 0: alpha0 = 0 at ST, -1e4 elsewhere, col ST = -1e4 so all
    // scores sit at ~-1e4:  A1_i = f0*L2E + IMIN*L2E + log2(1 + sum_j 2^T2_ij).
    // Anchor at rmc = max(rm,0): row EN has rm = -14427; a naive 2^(-rm)
    // guard overflows to inf. With rmc the S-term flushes to 0 and the
    // formula degrades gracefully to f0*L2E + IMIN*L2E (exact for row EN).
    float rmc = fmaxf(rm, 0.f);
    float A1 = fmaf(f0, L2E, (IMIN * L2E) + rmc +
                    log2f(fmaf(S, exp2f(rm - rmc), exp2f(-rmc))));

    if (i == 0) red[0] = A1;      // anchor row for the uniform shift
    __syncthreads();              // also covers featbuf[0] staging
    float sh = red[0];
    vbuf[0][i] = exp2f(A1 - sh);  // v[0]==1 at thread 0
    __syncthreads();

    int cur = 0;
    // prefetch chunk 1
    float4 fnA = *(const float4*)(fb + 1024 + i * 4);
    float4 fnB = *(const float4*)(fb + 1024 + 512 + i * 4);

    for (int ch = 0; ; ++ch) {
        if (8 * ch + 8 < L) {
            // stage chunk ch+1 into the buffer idle during this chunk;
            // the >=7 per-step barriers below order it before first read
            float* dst = featbuf[(ch + 1) & 1];
            *(float4*)(dst + i * 4) = fnA;
            *(float4*)(dst + 512 + i * 4) = fnB;
            int cn = min(8 * ch + 16, SS - 8);   // chunk ch+2 base step
            fnA = *(const float4*)(fb + cn * TT + i * 4);
            fnB = *(const float4*)(fb + cn * TT + 512 + i * 4);
        }
        const int sLo = (ch == 0) ? 1 : 8 * ch;
        const int sHi = min(8 * ch + 8, L);
        for (int s = sLo; s < sHi; ++s) {
            const float* vb = vbuf[cur];
            // chunk 0 carries vref = v[0]; cf chain overlaps the read stream
            float4 g0 = *(const float4*)(vb);
            float dsh = log2f(g0.x);
            float fv  = featbuf[ch & 1][((s & 7) << 7) + i];
            float cf  = exp2f(fmaf(fv, L2E, rm - dsh));

            float a0 = P[0].x * g0.x, a1 = P[0].y * g0.y;
            float a2 = P[0].z * g0.z, a3 = P[0].w * g0.w;
            float4 g1 = *(const float4*)(vb + 4);
            float a4 = P[1].x * g1.x, a5 = P[1].y * g1.y;
            float a6 = P[1].z * g1.z, a7 = P[1].w * g1.w;
            // chunks 2..31 as pairs (2,3),(4,6),...,(30,31) -- all in bounds
            #pragma unroll
            for (int k = 2; k < 32; k += 2) {
                float4 va = *(const float4*)(vb + 4 * k);
                a0 = fmaf(P[k].x, va.x, a0); a1 = fmaf(P[k].y, va.y, a1);
                a2 = fmaf(P[k].z, va.z, a2); a3 = fmaf(P[k].w, va.w, a3);
                float4 vc = *(const float4*)(vb + 4 * (k + 1));
                a4 = fmaf(P[k+1].x, vc.x, a4); a5 = fmaf(P[k+1].y, vc.y, a5);
                a6 = fmaf(P[k+1].z, vc.z, a6); a7 = fmaf(P[k+1].w, vc.w, a7);
            }
            float tot = ((a0 + a4) + (a1 + a5)) + ((a2 + a6) + (a3 + a7));
            float vn  = cf * tot;
            sh += dsh;
            vbuf[cur ^ 1][i] = vn;
            __syncthreads();
            cur ^= 1;
        }
        if (8 * ch + 8 >= L) break;
    }

    // epilogue: out = ln2 * log2 sum_j 2^(sh + log2 v_j + trans[EN][j]*L2E)
    float vL = vbuf[cur][i];
    float w  = fmaf(trans[EN * TT + i], L2E, sh + log2f(vL));  // v=0 -> -inf, benign
    float mm = w;
    #pragma unroll
    for (int off = 1; off < 64; off <<= 1) mm = fmaxf(mm, __shfl_xor(mm, off));
    if ((i & 63) == 0) red[1 + (i >> 6)] = mm;
    __syncthreads();
    mm = fmaxf(red[1], red[2]);
    float e = exp2f(w - mm);
    #pragma unroll
    for (int off = 1; off < 64; off <<= 1) e += __shfl_xor(e, off);
    if ((i & 63) == 0) red[4 + (i >> 6)] = e;
    __syncthreads();
    if (i == 0) out[b] = (mm + log2f(red[4] + red[5])) * LN2f;
}

extern "C" void kernel_launch(void* const* d_in, const int* in_sizes, int n_in,
                              void* d_out, int out_size, void* d_ws, size_t ws_size,
                              hipStream_t stream) {
    const float* feats = (const float*)d_in[0];
    const int*   blen  = (const int*)d_in[1];
    const float* trans = (const float*)d_in[2];
    float*       o     = (float*)d_out;
    crf_fwd<<<dim3(BB), dim3(128), 0, stream>>>(feats, blen, trans, o);
}

// Round 7
// 699.303 us; speedup vs baseline: 1.0036x; 1.0036x over previous
//
#include <hip/hip_runtime.h>

#define BB 256
#define SS 1024
#define TT 128
#define ST 126          // START state (column ST of trans = -1e4)
#define EN 127          // END state   (row EN of trans = -1e4)
#define IMIN -10000.0f
#define L2E 1.4426950408889634f
#define LN2f 0.6931471805599453f

// One block per batch, 128 threads (2 waves). Thread i owns state row i.
// P[i][j] = 2^(trans[i][j]*log2e - rm_i) held in 128 VGPRs (full row).
// __launch_bounds__(128, 1): 1 wave/EU min -> VGPR cap 512, so P does NOT
// spill (round 6 at default occupancy spilled: VGPR_Count=100 < 128 needed,
// scratch reloads on the critical path = 702us).
// v[j] = 2^(A[j] - sh) in LDS (128 floats), sh block-uniform (anchor = state 0).
// Per step:  tot_i = sum_j P[i][j] * v[j]        (128 in-lane FMAs)
//            dsh   = log2(v[0])                  (uniform, no reduce)
//            v'_i  = tot_i * 2^(feat_i*L2E + rm_i - dsh);   sh += dsh
__global__ __launch_bounds__(128, 1) void crf_fwd(const float* __restrict__ feats,
                                                  const int* __restrict__ blen,
                                                  const float* __restrict__ trans,
                                                  float* __restrict__ out)
{
    const int i = threadIdx.x;   // state row 0..127
    const int b = blockIdx.x;

    __shared__ __align__(16) float vbuf[2][TT];
    __shared__ __align__(16) float featbuf[2][8 * TT];
    __shared__ __align__(16) float red[8];

    const float* fb = feats + (size_t)b * (SS * TT);
    const int L = blen[b];

    // stage feature chunk 0 (steps 0..7): 1024 floats = 2 float4 per thread
    {
        float4 c0 = *(const float4*)(fb + i * 4);
        float4 c1 = *(const float4*)(fb + 512 + i * 4);
        *(float4*)(&featbuf[0][i * 4]) = c0;
        *(float4*)(&featbuf[0][512 + i * 4]) = c1;
    }
    float f0 = fb[i];   // step-0 feature, direct (coalesced dword)

    // full transition row -> registers, base-2 units
    float4 P[32];
    {
        const float* trow = trans + i * TT;
        #pragma unroll
        for (int k = 0; k < 32; ++k) {
            float4 tv = *(const float4*)(trow + 4 * k);
            P[k].x = tv.x * L2E; P[k].y = tv.y * L2E;
            P[k].z = tv.z * L2E; P[k].w = tv.w * L2E;
        }
    }
    float rm = -3.4e38f;
    #pragma unroll
    for (int k = 0; k < 32; ++k)
        rm = fmaxf(rm, fmaxf(fmaxf(P[k].x, P[k].y), fmaxf(P[k].z, P[k].w)));

    // normalize P and row-sum S
    float S = 0.f;
    #pragma unroll
    for (int k = 0; k < 32; ++k) {
        P[k].x = exp2f(P[k].x - rm); P[k].y = exp2f(P[k].y - rm);
        P[k].z = exp2f(P[k].z - rm); P[k].w = exp2f(P[k].w - rm);
        S += (P[k].x + P[k].y) + (P[k].z + P[k].w);
    }

    // exact step 0: alpha0 = 0 at ST, -1e4 elsewhere, col ST = -1e4 so all
    // scores sit at ~-1e4:  A1_i = f0*L2E + IMIN*L2E + log2(1 + sum_j 2^T2_ij).
    // Anchor at rmc = max(rm,0): row EN has rm = -14427; a naive 2^(-rm)
    // guard overflows to inf. With rmc the S-term flushes to 0 and the
    // formula degrades gracefully to f0*L2E + IMIN*L2E (exact for row EN).
    float rmc = fmaxf(rm, 0.f);
    float A1 = fmaf(f0, L2E, (IMIN * L2E) + rmc +
                    log2f(fmaf(S, exp2f(rm - rmc), exp2f(-rmc))));

    if (i == 0) red[0] = A1;      // anchor row for the uniform shift
    __syncthreads();              // also covers featbuf[0] staging
    float sh = red[0];
    vbuf[0][i] = exp2f(A1 - sh);  // v[0]==1 at thread 0
    __syncthreads();

    int cur = 0;
    // prefetch chunk 1
    float4 fnA = *(const float4*)(fb + 1024 + i * 4);
    float4 fnB = *(const float4*)(fb + 1024 + 512 + i * 4);

    for (int ch = 0; ; ++ch) {
        if (8 * ch + 8 < L) {
            // stage chunk ch+1 into the buffer idle during this chunk;
            // the >=7 per-step barriers below order it before first read
            float* dst = featbuf[(ch + 1) & 1];
            *(float4*)(dst + i * 4) = fnA;
            *(float4*)(dst + 512 + i * 4) = fnB;
            int cn = min(8 * ch + 16, SS - 8);   // chunk ch+2 base step
            fnA = *(const float4*)(fb + cn * TT + i * 4);
            fnB = *(const float4*)(fb + cn * TT + 512 + i * 4);
        }
        const int sLo = (ch == 0) ? 1 : 8 * ch;
        const int sHi = min(8 * ch + 8, L);
        for (int s = sLo; s < sHi; ++s) {
            const float* vb = vbuf[cur];
            // chunk 0 carries vref = v[0]; cf chain overlaps the read stream
            float4 g0 = *(const float4*)(vb);
            float dsh = log2f(g0.x);
            float fv  = featbuf[ch & 1][((s & 7) << 7) + i];
            float cf  = exp2f(fmaf(fv, L2E, rm - dsh));

            float a0 = P[0].x * g0.x, a1 = P[0].y * g0.y;
            float a2 = P[0].z * g0.z, a3 = P[0].w * g0.w;
            float4 g1 = *(const float4*)(vb + 4);
            float a4 = P[1].x * g1.x, a5 = P[1].y * g1.y;
            float a6 = P[1].z * g1.z, a7 = P[1].w * g1.w;
            // chunks 2..31 as pairs (2,3),(4,5),...,(30,31) -- all in bounds
            #pragma unroll
            for (int k = 2; k < 32; k += 2) {
                float4 va = *(const float4*)(vb + 4 * k);
                a0 = fmaf(P[k].x, va.x, a0); a1 = fmaf(P[k].y, va.y, a1);
                a2 = fmaf(P[k].z, va.z, a2); a3 = fmaf(P[k].w, va.w, a3);
                float4 vc = *(const float4*)(vb + 4 * (k + 1));
                a4 = fmaf(P[k+1].x, vc.x, a4); a5 = fmaf(P[k+1].y, vc.y, a5);
                a6 = fmaf(P[k+1].z, vc.z, a6); a7 = fmaf(P[k+1].w, vc.w, a7);
            }
            float tot = ((a0 + a4) + (a1 + a5)) + ((a2 + a6) + (a3 + a7));
            float vn  = cf * tot;
            sh += dsh;
            vbuf[cur ^ 1][i] = vn;
            __syncthreads();
            cur ^= 1;
        }
        if (8 * ch + 8 >= L) break;
    }

    // epilogue: out = ln2 * log2 sum_j 2^(sh + log2 v_j + trans[EN][j]*L2E)
    float vL = vbuf[cur][i];
    float w  = fmaf(trans[EN * TT + i], L2E, sh + log2f(vL));  // v=0 -> -inf, benign
    float mm = w;
    #pragma unroll
    for (int off = 1; off < 64; off <<= 1) mm = fmaxf(mm, __shfl_xor(mm, off));
    if ((i & 63) == 0) red[1 + (i >> 6)] = mm;
    __syncthreads();
    mm = fmaxf(red[1], red[2]);
    float e = exp2f(w - mm);
    #pragma unroll
    for (int off = 1; off < 64; off <<= 1) e += __shfl_xor(e, off);
    if ((i & 63) == 0) red[4 + (i >> 6)] = e;
    __syncthreads();
    if (i == 0) out[b] = (mm + log2f(red[4] + red[5])) * LN2f;
}

extern "C" void kernel_launch(void* const* d_in, const int* in_sizes, int n_in,
                              void* d_out, int out_size, void* d_ws, size_t ws_size,
                              hipStream_t stream) {
    const float* feats = (const float*)d_in[0];
    const int*   blen  = (const int*)d_in[1];
    const float* trans = (const float*)d_in[2];
    float*       o     = (float*)d_out;
    crf_fwd<<<dim3(BB), dim3(128), 0, stream>>>(feats, blen, trans, o);
}

// Round 8
// 372.273 us; speedup vs baseline: 1.8852x; 1.8785x over previous
//
#include <hip/hip_runtime.h>

#define BB 256
#define SS 1024
#define TT 128
#define ST 126          // START state (column ST of trans = -1e4)
#define EN 127          // END state   (row EN of trans = -1e4)
#define IMIN -10000.0f
#define L2E 1.4426950408889634f
#define LN2f 0.6931471805599453f
#define QS 40           // padded quarter stride (floats); quarter bases hit
                        // disjoint bank groups (r3: zero conflicts)

// One block per batch, 512 threads (8 waves, 2/SIMD). tid = 4*i + q:
// i = state row (0..127), q = j-quarter. P quarter-row (8 float4) per thread
// -> no VGPR pressure, all 8 LDS reads batch into ONE latency exposure
// (r6/r7 failure: 32 reads vs ~100 VGPRs forced grouped read->wait->FMA,
// paying ~120cy LDS latency ~8x per step with no sibling wave to hide it).
// v[j] = 2^(A[j]-sh) in LDS, sh block-uniform, anchored at state 0:
// dsh = log2(v[0]) -- uniform, NO reduce (r6's trick, exact accounting).
// Quad combine via __shfl_xor 1/2 -> DPP quad-perm (VALU, no DS traffic).
__global__ __launch_bounds__(512, 1) void crf_fwd(const float* __restrict__ feats,
                                                  const int* __restrict__ blen,
                                                  const float* __restrict__ trans,
                                                  float* __restrict__ out)
{
    const int tid = threadIdx.x;
    const int i   = tid >> 2;    // state row
    const int q   = tid & 3;     // j-quarter
    const int b   = blockIdx.x;

    __shared__ __align__(16) float vbuf[2][4 * QS];
    __shared__ __align__(16) float featbuf[2][8 * TT];
    __shared__ __align__(16) float wout[TT];
    __shared__ __align__(16) float red[8];

    const float* fb = feats + (size_t)b * (SS * TT);
    const int L = blen[b];

    // stage feature chunk 0 (steps 0..7): 512 threads x float2 = 1024 floats
    *(float2*)(&featbuf[0][tid * 2]) = *(const float2*)(fb + tid * 2);
    float f0 = fb[i];   // step-0 feature (quad-broadcast dword)

    // quarter transition row -> registers, base-2 units
    float4 P[8];
    {
        const float* trow = trans + i * TT + q * 32;
        #pragma unroll
        for (int k = 0; k < 8; ++k) {
            float4 tv = *(const float4*)(trow + 4 * k);
            P[k].x = tv.x * L2E; P[k].y = tv.y * L2E;
            P[k].z = tv.z * L2E; P[k].w = tv.w * L2E;
        }
    }
    // full-row max via quad reduce (DPP)
    float rm = -3.4e38f;
    #pragma unroll
    for (int k = 0; k < 8; ++k)
        rm = fmaxf(rm, fmaxf(fmaxf(P[k].x, P[k].y), fmaxf(P[k].z, P[k].w)));
    rm = fmaxf(rm, __shfl_xor(rm, 1));
    rm = fmaxf(rm, __shfl_xor(rm, 2));

    // normalize P, full-row sum S via quad reduce
    float S = 0.f;
    #pragma unroll
    for (int k = 0; k < 8; ++k) {
        P[k].x = exp2f(P[k].x - rm); P[k].y = exp2f(P[k].y - rm);
        P[k].z = exp2f(P[k].z - rm); P[k].w = exp2f(P[k].w - rm);
        S += (P[k].x + P[k].y) + (P[k].z + P[k].w);
    }
    S += __shfl_xor(S, 1);
    S += __shfl_xor(S, 2);

    // exact step 0 (alpha0 = delta on ST, col ST = -1e4 -> all scores ~ -1e4):
    // A1_i = f0*L2E + IMIN*L2E + log2(1 + sum_j 2^T2_ij), anchored at
    // rmc=max(rm,0) so row EN (rm=-14427) degrades gracefully (r4 NaN fix).
    float rmc = fmaxf(rm, 0.f);
    float A1 = fmaf(f0, L2E, (IMIN * L2E) + rmc +
                    log2f(fmaf(S, exp2f(rm - rmc), exp2f(-rmc))));

    if (tid == 0) red[0] = A1;    // anchor row for the uniform shift
    __syncthreads();              // also covers featbuf[0] staging
    float sh = red[0];
    if (q == 0) vbuf[0][(i >> 5) * QS + (i & 31)] = exp2f(A1 - sh); // v[0]=1 @ i=0
    __syncthreads();

    int cur = 0;
    float2 fnx = *(const float2*)(fb + 8 * TT + tid * 2);  // prefetch chunk 1

    for (int ch = 0; ; ++ch) {
        if (8 * ch + 8 < L) {
            // stage chunk ch+1 into the idle buffer; step barriers below
            // order it before its first read (r6-proven pattern)
            *(float2*)(&featbuf[(ch + 1) & 1][tid * 2]) = fnx;
            int cn = min(8 * ch + 16, SS - 8);
            fnx = *(const float2*)(fb + cn * TT + tid * 2);
        }
        const int sLo = (ch == 0) ? 1 : 8 * ch;
        const int sHi = min(8 * ch + 8, L);
        for (int s = sLo; s < sHi; ++s) {
            const float* vb = &vbuf[cur][q * QS];
            // issue anchor + feature reads first; cf chain runs under the FMAs
            float v0f = vbuf[cur][0];
            float fv  = featbuf[ch & 1][((s & 7) << 7) + i];
            float dsh = log2f(v0f);
            float cf  = exp2f(fmaf(fv, L2E, rm - dsh));

            // matvec quarter: 8 b128 reads batch into one latency exposure
            float a0 = 0.f, a1 = 0.f, a2 = 0.f, a3 = 0.f;
            #pragma unroll
            for (int k = 0; k < 8; ++k) {
                float4 vv = *(const float4*)(vb + 4 * k);
                a0 = fmaf(P[k].x, vv.x, a0);
                a1 = fmaf(P[k].y, vv.y, a1);
                a2 = fmaf(P[k].z, vv.z, a2);
                a3 = fmaf(P[k].w, vv.w, a3);
            }
            float part = (a0 + a1) + (a2 + a3);
            part += __shfl_xor(part, 1);   // DPP quad-perm, no DS
            part += __shfl_xor(part, 2);

            float vn = cf * part;
            sh += dsh;
            if (q == 0) vbuf[cur ^ 1][(i >> 5) * QS + (i & 31)] = vn;
            __syncthreads();               // single barrier per step
            cur ^= 1;
        }
        if (8 * ch + 8 >= L) break;
    }

    // epilogue: out = ln2 * log2 sum_j 2^(sh + log2 v_j + trans[EN][j]*L2E)
    float vL = vbuf[cur][(i >> 5) * QS + (i & 31)];
    float w  = fmaf(trans[EN * TT + i], L2E, sh + log2f(vL)); // v=0 -> -inf ok
    if (q == 0) wout[i] = w;
    __syncthreads();
    if (tid < 64) {
        float w0 = wout[tid], w1 = wout[tid + 64];
        float mm = fmaxf(w0, w1);
        #pragma unroll
        for (int off = 1; off < 64; off <<= 1) mm = fmaxf(mm, __shfl_xor(mm, off));
        float ss = exp2f(w0 - mm) + exp2f(w1 - mm);
        #pragma unroll
        for (int off = 1; off < 64; off <<= 1) ss += __shfl_xor(ss, off);
        if (tid == 0) out[b] = (mm + log2f(ss)) * LN2f;
    }
}

extern "C" void kernel_launch(void* const* d_in, const int* in_sizes, int n_in,
                              void* d_out, int out_size, void* d_ws, size_t ws_size,
                              hipStream_t stream) {
    const float* feats = (const float*)d_in[0];
    const int*   blen  = (const int*)d_in[1];
    const float* trans = (const float*)d_in[2];
    float*       o     = (float*)d_out;
    crf_fwd<<<dim3(BB), dim3(512), 0, stream>>>(feats, blen, trans, o);
}

// Round 9
// 356.950 us; speedup vs baseline: 1.9661x; 1.0429x over previous
//
#include <hip/hip_runtime.h>

#define BB 256
#define SS 1024
#define TT 128
#define ST 126          // START state (column ST of trans = -1e4)
#define EN 127          // END state   (row EN of trans = -1e4)
#define IMIN -10000.0f
#define L2E 1.4426950408889634f
#define LN2f 0.6931471805599453f
#define QS 40           // padded quarter stride (floats); quarter bases hit
                        // disjoint bank groups (r3/r8: zero conflicts)

// One block per batch, 512 threads (8 waves, 2/SIMD). tid = 4*i + q:
// i = state row (0..127), q = j-quarter (32 P-coeffs per thread).
// v[j] = 2^(A[j]-sh) in LDS, sh block-uniform, anchored at state 0:
// dsh = log2(v[0]) -- uniform, NO reduce. Quad combine = DPP shuffles.
// r8 lesson (VGPR_Count=40): compiler grouped the 8 ds_read_b128 into
// several read->wait->FMA clusters, paying LDS latency 3-4x per step.
// This version loads all 8 float4 into NAMED locals before any FMA so
// the reads issue back-to-back (one latency exposure, lgkmcnt-overlapped).
__global__ __launch_bounds__(512, 1) void crf_fwd(const float* __restrict__ feats,
                                                  const int* __restrict__ blen,
                                                  const float* __restrict__ trans,
                                                  float* __restrict__ out)
{
    const int tid = threadIdx.x;
    const int i   = tid >> 2;    // state row
    const int q   = tid & 3;     // j-quarter
    const int b   = blockIdx.x;

    __shared__ __align__(16) float vbuf[2][4 * QS];
    __shared__ __align__(16) float featbuf[2][8 * TT];
    __shared__ __align__(16) float wout[TT];
    __shared__ __align__(16) float red[8];

    const float* fb = feats + (size_t)b * (SS * TT);
    const int L = blen[b];

    // stage feature chunk 0 (steps 0..7): 512 threads x float2 = 1024 floats
    *(float2*)(&featbuf[0][tid * 2]) = *(const float2*)(fb + tid * 2);
    float f0 = fb[i];   // step-0 feature (quad-broadcast dword)

    // quarter transition row -> registers, base-2 units
    float4 P0, P1, P2, P3, P4, P5, P6, P7;
    {
        const float* trow = trans + i * TT + q * 32;
        P0 = *(const float4*)(trow);      P1 = *(const float4*)(trow + 4);
        P2 = *(const float4*)(trow + 8);  P3 = *(const float4*)(trow + 12);
        P4 = *(const float4*)(trow + 16); P5 = *(const float4*)(trow + 20);
        P6 = *(const float4*)(trow + 24); P7 = *(const float4*)(trow + 28);
    }
#define SCALE4(Pv) Pv.x *= L2E; Pv.y *= L2E; Pv.z *= L2E; Pv.w *= L2E
    SCALE4(P0); SCALE4(P1); SCALE4(P2); SCALE4(P3);
    SCALE4(P4); SCALE4(P5); SCALE4(P6); SCALE4(P7);
#undef SCALE4

    // full-row max via quad reduce (DPP)
    float rm = -3.4e38f;
#define MAX4(Pv) rm = fmaxf(rm, fmaxf(fmaxf(Pv.x, Pv.y), fmaxf(Pv.z, Pv.w)))
    MAX4(P0); MAX4(P1); MAX4(P2); MAX4(P3);
    MAX4(P4); MAX4(P5); MAX4(P6); MAX4(P7);
#undef MAX4
    rm = fmaxf(rm, __shfl_xor(rm, 1));
    rm = fmaxf(rm, __shfl_xor(rm, 2));

    // normalize P, full-row sum S via quad reduce
    float S = 0.f;
#define NORM4(Pv) Pv.x = exp2f(Pv.x - rm); Pv.y = exp2f(Pv.y - rm); \
                  Pv.z = exp2f(Pv.z - rm); Pv.w = exp2f(Pv.w - rm); \
                  S += (Pv.x + Pv.y) + (Pv.z + Pv.w)
    NORM4(P0); NORM4(P1); NORM4(P2); NORM4(P3);
    NORM4(P4); NORM4(P5); NORM4(P6); NORM4(P7);
#undef NORM4
    S += __shfl_xor(S, 1);
    S += __shfl_xor(S, 2);

    // exact step 0 (alpha0 = delta on ST, col ST = -1e4 -> all scores ~ -1e4):
    // A1_i = f0*L2E + IMIN*L2E + log2(1 + sum_j 2^T2_ij), anchored at
    // rmc=max(rm,0) so row EN (rm=-14427) degrades gracefully (r4 NaN fix).
    float rmc = fmaxf(rm, 0.f);
    float A1 = fmaf(f0, L2E, (IMIN * L2E) + rmc +
                    log2f(fmaf(S, exp2f(rm - rmc), exp2f(-rmc))));

    if (tid == 0) red[0] = A1;    // anchor row for the uniform shift
    __syncthreads();              // also covers featbuf[0] staging
    float sh = red[0];
    if (q == 0) vbuf[0][(i >> 5) * QS + (i & 31)] = exp2f(A1 - sh); // v[0]=1 @ i=0
    __syncthreads();

    int cur = 0;
    float2 fnx = *(const float2*)(fb + 8 * TT + tid * 2);  // prefetch chunk 1

    for (int ch = 0; ; ++ch) {
        if (8 * ch + 8 < L) {
            // stage chunk ch+1 into the idle buffer; step barriers below
            // order it before its first read
            *(float2*)(&featbuf[(ch + 1) & 1][tid * 2]) = fnx;
            int cn = min(8 * ch + 16, SS - 8);
            fnx = *(const float2*)(fb + cn * TT + tid * 2);
        }
        const int sLo = (ch == 0) ? 1 : 8 * ch;
        const int sHi = min(8 * ch + 8, L);
        for (int s = sLo; s < sHi; ++s) {
            const float* vb = &vbuf[cur][q * QS];
            // ALL reads issued before any consumer: one latency exposure
            float v0f = vbuf[cur][0];
            float fv  = featbuf[ch & 1][((s & 7) << 7) + i];
            float4 v0 = *(const float4*)(vb);
            float4 v1 = *(const float4*)(vb + 4);
            float4 v2 = *(const float4*)(vb + 8);
            float4 v3 = *(const float4*)(vb + 12);
            float4 v4 = *(const float4*)(vb + 16);
            float4 v5 = *(const float4*)(vb + 20);
            float4 v6 = *(const float4*)(vb + 24);
            float4 v7 = *(const float4*)(vb + 28);

            float dsh = log2f(v0f);
            float cf  = exp2f(fmaf(fv, L2E, rm - dsh));

            float a0 = P0.x * v0.x, a1 = P0.y * v0.y;
            float a2 = P0.z * v0.z, a3 = P0.w * v0.w;
            a0 = fmaf(P1.x, v1.x, a0); a1 = fmaf(P1.y, v1.y, a1);
            a2 = fmaf(P1.z, v1.z, a2); a3 = fmaf(P1.w, v1.w, a3);
            a0 = fmaf(P2.x, v2.x, a0); a1 = fmaf(P2.y, v2.y, a1);
            a2 = fmaf(P2.z, v2.z, a2); a3 = fmaf(P2.w, v2.w, a3);
            a0 = fmaf(P3.x, v3.x, a0); a1 = fmaf(P3.y, v3.y, a1);
            a2 = fmaf(P3.z, v3.z, a2); a3 = fmaf(P3.w, v3.w, a3);
            a0 = fmaf(P4.x, v4.x, a0); a1 = fmaf(P4.y, v4.y, a1);
            a2 = fmaf(P4.z, v4.z, a2); a3 = fmaf(P4.w, v4.w, a3);
            a0 = fmaf(P5.x, v5.x, a0); a1 = fmaf(P5.y, v5.y, a1);
            a2 = fmaf(P5.z, v5.z, a2); a3 = fmaf(P5.w, v5.w, a3);
            a0 = fmaf(P6.x, v6.x, a0); a1 = fmaf(P6.y, v6.y, a1);
            a2 = fmaf(P6.z, v6.z, a2); a3 = fmaf(P6.w, v6.w, a3);
            a0 = fmaf(P7.x, v7.x, a0); a1 = fmaf(P7.y, v7.y, a1);
            a2 = fmaf(P7.z, v7.z, a2); a3 = fmaf(P7.w, v7.w, a3);

            float part = (a0 + a1) + (a2 + a3);
            part += __shfl_xor(part, 1);   // DPP quad-perm, no DS
            part += __shfl_xor(part, 2);

            float vn = cf * part;
            sh += dsh;
            if (q == 0) vbuf[cur ^ 1][(i >> 5) * QS + (i & 31)] = vn;
            __syncthreads();               // single barrier per step
            cur ^= 1;
        }
        if (8 * ch + 8 >= L) break;
    }

    // epilogue: out = ln2 * log2 sum_j 2^(sh + log2 v_j + trans[EN][j]*L2E)
    float vL = vbuf[cur][(i >> 5) * QS + (i & 31)];
    float w  = fmaf(trans[EN * TT + i], L2E, sh + log2f(vL)); // v=0 -> -inf ok
    if (q == 0) wout[i] = w;
    __syncthreads();
    if (tid < 64) {
        float w0 = wout[tid], w1 = wout[tid + 64];
        float mm = fmaxf(w0, w1);
        #pragma unroll
        for (int off = 1; off < 64; off <<= 1) mm = fmaxf(mm, __shfl_xor(mm, off));
        float ss = exp2f(w0 - mm) + exp2f(w1 - mm);
        #pragma unroll
        for (int off = 1; off < 64; off <<= 1) ss += __shfl_xor(ss, off);
        if (tid == 0) out[b] = (mm + log2f(ss)) * LN2f;
    }
}

extern "C" void kernel_launch(void* const* d_in, const int* in_sizes, int n_in,
                              void* d_out, int out_size, void* d_ws, size_t ws_size,
                              hipStream_t stream) {
    const float* feats = (const float*)d_in[0];
    const int*   blen  = (const int*)d_in[1];
    const float* trans = (const float*)d_in[2];
    float*       o     = (float*)d_out;
    crf_fwd<<<dim3(BB), dim3(512), 0, stream>>>(feats, blen, trans, o);
}